// Round 1
// baseline (254.228 us; speedup 1.0000x reference)
//
#include <hip/hip_runtime.h>
#include <hip/hip_bf16.h>
#include <math.h>

// SelfAttention: out = softmax(mask(q k^T)/32) v, q=xWq^T k=xWk^T v=xWv^T
// N=4096 tokens, E=1024. bf16 MFMA compute, fp32 accumulate.

typedef __attribute__((ext_vector_type(8))) __bf16 bf16x8;
typedef __attribute__((ext_vector_type(4))) __bf16 bf16x4;
typedef __attribute__((ext_vector_type(4))) float f32x4;

__device__ __forceinline__ void gload_lds16(const void* g, void* l) {
  __builtin_amdgcn_global_load_lds(
      (__attribute__((address_space(1))) void*)(g),
      (__attribute__((address_space(3))) void*)(l), 16, 0, 0);
}

__global__ __launch_bounds__(256) void cvt_f32_bf16(const float* __restrict__ in,
                                                    __bf16* __restrict__ out, int n4) {
  int i = blockIdx.x * 256 + threadIdx.x;
  if (i >= n4) return;
  float4 f = ((const float4*)in)[i];
  bf16x4 o;
  o[0] = (__bf16)f.x; o[1] = (__bf16)f.y; o[2] = (__bf16)f.z; o[3] = (__bf16)f.w;
  ((bf16x4*)out)[i] = o;
}

// B^T-form GEMM: C[r][c] = sum_k A[r][k] * B[c][k]
// Tile 128x128, BK=64, 4 waves each computing 64x64 (4x4 frags of 16x16x32).
// EPI 0: store bf16. EPI 2: store f32.
template <int EPI>
__global__ __launch_bounds__(256) void gemm_bt(const __bf16* __restrict__ A, int lda,
                                               const __bf16* __restrict__ B, int ldb,
                                               void* __restrict__ Cp, int ldc, int K) {
  __shared__ __bf16 lsA[128 * 64];
  __shared__ __bf16 lsB[128 * 64];
  const int tid = threadIdx.x;
  const int lane = tid & 63;
  const int w = tid >> 6;
  const int wr = w >> 1, wc = w & 1;
  const long row0 = (long)blockIdx.y * 128;
  const long col0 = (long)blockIdx.x * 128;
  const int hi = lane >> 4;  // 0..3 (k-chunk for frags)
  const int lo = lane & 15;  // row-within-16

  f32x4 acc[4][4] = {};

  for (int k0 = 0; k0 < K; k0 += 64) {
#pragma unroll
    for (int i = 0; i < 4; ++i) {
      int c = i * 256 + tid;          // chunk index (16B chunks), per-lane
      int r = c >> 3, cv = c & 7;     // row in tile, 8-elem col group
      gload_lds16(A + (row0 + r) * lda + k0 + cv * 8,
                  lsA + (i * 256 + w * 64) * 8);  // wave-uniform LDS base
    }
#pragma unroll
    for (int i = 0; i < 4; ++i) {
      int c = i * 256 + tid;
      int r = c >> 3, cv = c & 7;
      gload_lds16(B + (col0 + r) * ldb + k0 + cv * 8,
                  lsB + (i * 256 + w * 64) * 8);
    }
    __syncthreads();
#pragma unroll
    for (int kk = 0; kk < 64; kk += 32) {
      bf16x8 af[4], bfr[4];
#pragma unroll
      for (int m = 0; m < 4; ++m)
        af[m] = *(const bf16x8*)(lsA + (wr * 64 + m * 16 + lo) * 64 + kk + hi * 8);
#pragma unroll
      for (int n = 0; n < 4; ++n)
        bfr[n] = *(const bf16x8*)(lsB + (wc * 64 + n * 16 + lo) * 64 + kk + hi * 8);
#pragma unroll
      for (int m = 0; m < 4; ++m)
#pragma unroll
        for (int n = 0; n < 4; ++n)
          acc[m][n] = __builtin_amdgcn_mfma_f32_16x16x32_bf16(af[m], bfr[n], acc[m][n], 0, 0, 0);
    }
    __syncthreads();
  }

  // C/D layout (verified m89/m91): col = lane&15, row = (lane>>4)*4 + i
#pragma unroll
  for (int m = 0; m < 4; ++m)
#pragma unroll
    for (int n = 0; n < 4; ++n)
#pragma unroll
      for (int i = 0; i < 4; ++i) {
        long r = row0 + wr * 64 + m * 16 + hi * 4 + i;
        long cc = col0 + wc * 64 + n * 16 + lo;
        float v = acc[m][n][i];
        if (EPI == 0)
          ((__bf16*)Cp)[r * ldc + cc] = (__bf16)v;
        else
          ((float*)Cp)[r * ldc + cc] = v;
      }
}

// One block per row: mask (-1e20 where mask==0), stable softmax of row/32,
// write attn as bf16 IN-PLACE over the fp32 row (attn ld = 8192 bf16 elems).
__global__ __launch_bounds__(256) void softmax_rows(float* __restrict__ sim,
                                                    const int* __restrict__ mask) {
  const int row = blockIdx.x;
  float* rp = sim + (size_t)row * 4096;
  const int4* mrow = (const int4*)(mask + (size_t)row * 4096);
  const int tid = threadIdx.x;

  float vals[16];
  float lmax = -INFINITY;
#pragma unroll
  for (int j = 0; j < 4; ++j) {
    float4 f = ((const float4*)rp)[tid + 256 * j];
    int4 mm = mrow[tid + 256 * j];
    f.x = mm.x ? f.x : -1e20f;
    f.y = mm.y ? f.y : -1e20f;
    f.z = mm.z ? f.z : -1e20f;
    f.w = mm.w ? f.w : -1e20f;
    vals[4 * j + 0] = f.x; vals[4 * j + 1] = f.y;
    vals[4 * j + 2] = f.z; vals[4 * j + 3] = f.w;
    lmax = fmaxf(lmax, fmaxf(fmaxf(f.x, f.y), fmaxf(f.z, f.w)));
  }
#pragma unroll
  for (int off = 32; off; off >>= 1) lmax = fmaxf(lmax, __shfl_xor(lmax, off));
  __shared__ float red[4];
  __shared__ float bro[2];
  if ((tid & 63) == 0) red[tid >> 6] = lmax;
  __syncthreads();
  if (tid == 0) bro[0] = fmaxf(fmaxf(red[0], red[1]), fmaxf(red[2], red[3]));
  __syncthreads();
  const float m = bro[0];

  float e[16];
  float lsum = 0.f;
#pragma unroll
  for (int j = 0; j < 16; ++j) {
    e[j] = __expf((vals[j] - m) * 0.03125f);  // /sqrt(1024)
    lsum += e[j];
  }
#pragma unroll
  for (int off = 32; off; off >>= 1) lsum += __shfl_xor(lsum, off);
  if ((tid & 63) == 0) red[tid >> 6] = lsum;
  __syncthreads();
  if (tid == 0) bro[1] = red[0] + red[1] + red[2] + red[3];
  __syncthreads();
  const float inv = 1.0f / bro[1];

  __bf16* op = (__bf16*)rp;
#pragma unroll
  for (int j = 0; j < 4; ++j) {
    bf16x4 o;
    o[0] = (__bf16)(e[4 * j + 0] * inv);
    o[1] = (__bf16)(e[4 * j + 1] * inv);
    o[2] = (__bf16)(e[4 * j + 2] * inv);
    o[3] = (__bf16)(e[4 * j + 3] * inv);
    ((bf16x4*)op)[tid + 256 * j] = o;
  }
}

extern "C" void kernel_launch(void* const* d_in, const int* in_sizes, int n_in,
                              void* d_out, int out_size, void* d_ws, size_t ws_size,
                              hipStream_t stream) {
  const float* x = (const float*)d_in[0];
  const int* mask = (const int*)d_in[1];
  const float* Wq = (const float*)d_in[2];
  const float* Wk = (const float*)d_in[3];
  const float* Wv = (const float*)d_in[4];
  float* out = (float*)d_out;

  // Workspace layout (needs 102 MB):
  // [0,2M)   Wq bf16   [2M,4M)  Wk bf16   [4M,6M)  Wv bf16
  // [6M,14M) x bf16    [14M,22M) q bf16   [22M,30M) k bf16
  // [30M,38M) vT bf16  [38M,102M) sim fp32 (attn bf16 written in-place, ld 8192)
  char* ws = (char*)d_ws;
  __bf16* wqb = (__bf16*)(ws);
  __bf16* wkb = (__bf16*)(ws + (2ull << 20));
  __bf16* wvb = (__bf16*)(ws + (4ull << 20));
  __bf16* xb  = (__bf16*)(ws + (6ull << 20));
  __bf16* qb  = (__bf16*)(ws + (14ull << 20));
  __bf16* kb  = (__bf16*)(ws + (22ull << 20));
  __bf16* vtb = (__bf16*)(ws + (30ull << 20));
  float*  sim = (float*)(ws + (38ull << 20));

  cvt_f32_bf16<<<4096, 256, 0, stream>>>(x, xb, 1048576);
  cvt_f32_bf16<<<1024, 256, 0, stream>>>(Wq, wqb, 262144);
  cvt_f32_bf16<<<1024, 256, 0, stream>>>(Wk, wkb, 262144);
  cvt_f32_bf16<<<1024, 256, 0, stream>>>(Wv, wvb, 262144);

  dim3 blk(256);
  // q[i][j] = sum_e x[i,e] Wq[j,e]   (M=4096, N=1024)
  gemm_bt<0><<<dim3(8, 32), blk, 0, stream>>>(xb, 1024, wqb, 1024, qb, 1024, 1024);
  gemm_bt<0><<<dim3(8, 32), blk, 0, stream>>>(xb, 1024, wkb, 1024, kb, 1024, 1024);
  // vT[j][i] = sum_e Wv[j,e] x[i,e]  (M=1024, N=4096) — v stored transposed
  gemm_bt<0><<<dim3(32, 8), blk, 0, stream>>>(wvb, 1024, xb, 1024, vtb, 4096, 1024);
  // sim[i][j] = sum_e q[i,e] k[j,e]  (M=N=4096), raw fp32
  gemm_bt<2><<<dim3(32, 32), blk, 0, stream>>>(qb, 1024, kb, 1024, sim, 4096, 1024);
  // masked softmax, attn bf16 in-place (ld 8192)
  softmax_rows<<<4096, 256, 0, stream>>>(sim, mask);
  // out[i][j] = sum_k attn[i,k] vT[j,k]  (M=4096, N=1024, K=4096)
  gemm_bt<2><<<dim3(8, 32), blk, 0, stream>>>((const __bf16*)sim, 8192, vtb, 4096, out, 1024, 4096);
}

// Round 2
// 209.270 us; speedup vs baseline: 1.2148x; 1.2148x over previous
//
#include <hip/hip_runtime.h>
#include <hip/hip_bf16.h>
#include <math.h>

// SelfAttention: out = softmax(mask(q k^T)/32) v, q=xWq^T k=xWk^T v=xWv^T
// N=4096 tokens, E=1024. bf16 MFMA compute, fp32 accumulate.
// R2: PV split-K x2 (512 blocks), fused QKV (768 blocks), fused cvt.

typedef __attribute__((ext_vector_type(8))) __bf16 bf16x8;
typedef __attribute__((ext_vector_type(4))) __bf16 bf16x4;
typedef __attribute__((ext_vector_type(4))) float f32x4;

__device__ __forceinline__ void gload_lds16(const void* g, void* l) {
  __builtin_amdgcn_global_load_lds(
      (__attribute__((address_space(1))) void*)(g),
      (__attribute__((address_space(3))) void*)(l), 16, 0, 0);
}

// One launch converts x, Wq, Wk, Wv to bf16. Blocks partitioned by range.
__global__ __launch_bounds__(256) void cvt_all(const float* __restrict__ x,
                                               const float* __restrict__ wq,
                                               const float* __restrict__ wk,
                                               const float* __restrict__ wv,
                                               __bf16* __restrict__ xb,
                                               __bf16* __restrict__ wqb,
                                               __bf16* __restrict__ wkb,
                                               __bf16* __restrict__ wvb) {
  int b = blockIdx.x;
  const float* in;
  __bf16* out;
  int base;
  if (b < 4096)      { in = x;  out = xb;  base = b; }
  else if (b < 5120) { in = wq; out = wqb; base = b - 4096; }
  else if (b < 6144) { in = wk; out = wkb; base = b - 5120; }
  else               { in = wv; out = wvb; base = b - 6144; }
  int i = base * 256 + threadIdx.x;
  float4 f = ((const float4*)in)[i];
  bf16x4 o;
  o[0] = (__bf16)f.x; o[1] = (__bf16)f.y; o[2] = (__bf16)f.z; o[3] = (__bf16)f.w;
  ((bf16x4*)out)[i] = o;
}

// ---- shared GEMM macro-structure: B^T-form, tile 128x128, BK=64, 4 waves ----
// Staging: 4+4 global_load_lds x16B per thread per K-step; LDS [128][64] bf16.

#define GEMM_PROLOGUE()                                   \
  __shared__ __bf16 lsA[128 * 64];                        \
  __shared__ __bf16 lsB[128 * 64];                        \
  const int tid = threadIdx.x;                            \
  const int lane = tid & 63;                              \
  const int w = tid >> 6;                                 \
  const int wr = w >> 1, wc = w & 1;                      \
  const int hi = lane >> 4;                               \
  const int lo = lane & 15;                               \
  f32x4 acc[4][4] = {};

#define GEMM_KSTEP(Aptr, lda, Bptr, ldb, k0)              \
  {                                                       \
    _Pragma("unroll") for (int i = 0; i < 4; ++i) {       \
      int c = i * 256 + tid;                              \
      int r = c >> 3, cv = c & 7;                         \
      gload_lds16((Aptr) + (row0 + r) * (long)(lda) + (k0) + cv * 8, \
                  lsA + (i * 256 + w * 64) * 8);          \
    }                                                     \
    _Pragma("unroll") for (int i = 0; i < 4; ++i) {       \
      int c = i * 256 + tid;                              \
      int r = c >> 3, cv = c & 7;                         \
      gload_lds16((Bptr) + (col0 + r) * (long)(ldb) + (k0) + cv * 8, \
                  lsB + (i * 256 + w * 64) * 8);          \
    }                                                     \
    __syncthreads();                                      \
    _Pragma("unroll") for (int kk = 0; kk < 64; kk += 32) { \
      bf16x8 af[4], bfr[4];                               \
      _Pragma("unroll") for (int m = 0; m < 4; ++m)       \
        af[m] = *(const bf16x8*)(lsA + (wr * 64 + m * 16 + lo) * 64 + kk + hi * 8); \
      _Pragma("unroll") for (int n = 0; n < 4; ++n)       \
        bfr[n] = *(const bf16x8*)(lsB + (wc * 64 + n * 16 + lo) * 64 + kk + hi * 8); \
      _Pragma("unroll") for (int m = 0; m < 4; ++m)       \
        _Pragma("unroll") for (int n = 0; n < 4; ++n)     \
          acc[m][n] = __builtin_amdgcn_mfma_f32_16x16x32_bf16(af[m], bfr[n], acc[m][n], 0, 0, 0); \
    }                                                     \
    __syncthreads();                                      \
  }

// sim GEMM: C[r][c] = sum_k A[r][k]*B[c][k], fp32 store.
__global__ __launch_bounds__(256) void gemm_bt_f32(const __bf16* __restrict__ A, int lda,
                                                   const __bf16* __restrict__ B, int ldb,
                                                   float* __restrict__ C, int ldc, int K) {
  const long row0 = (long)blockIdx.y * 128;
  const long col0 = (long)blockIdx.x * 128;
  GEMM_PROLOGUE();
  for (int k0 = 0; k0 < K; k0 += 64) GEMM_KSTEP(A, lda, B, ldb, k0);
#pragma unroll
  for (int m = 0; m < 4; ++m)
#pragma unroll
    for (int n = 0; n < 4; ++n)
#pragma unroll
      for (int i = 0; i < 4; ++i) {
        long r = row0 + wr * 64 + m * 16 + hi * 4 + i;
        long cc = col0 + wc * 64 + n * 16 + lo;
        C[r * (long)ldc + cc] = acc[m][n][i];
      }
}

// Fused QKV: z=0 -> q, z=1 -> k, z=2 -> v stored TRANSPOSED (vT [1024][4096]).
// All: M=4096 tokens (y), N=1024 (x), K=1024.
__global__ __launch_bounds__(256) void qkv_gemm(const __bf16* __restrict__ xb,
                                                const __bf16* __restrict__ wq,
                                                const __bf16* __restrict__ wk,
                                                const __bf16* __restrict__ wv,
                                                __bf16* __restrict__ qb,
                                                __bf16* __restrict__ kb,
                                                __bf16* __restrict__ vtb) {
  const int z = blockIdx.z;
  const __bf16* Bw = (z == 0) ? wq : (z == 1) ? wk : wv;
  const long row0 = (long)blockIdx.y * 128;
  const long col0 = (long)blockIdx.x * 128;
  GEMM_PROLOGUE();
  for (int k0 = 0; k0 < 1024; k0 += 64) GEMM_KSTEP(xb, 1024, Bw, 1024, k0);
#pragma unroll
  for (int m = 0; m < 4; ++m)
#pragma unroll
    for (int n = 0; n < 4; ++n)
#pragma unroll
      for (int i = 0; i < 4; ++i) {
        long r = row0 + wr * 64 + m * 16 + hi * 4 + i;   // token index
        long cc = col0 + wc * 64 + n * 16 + lo;          // feature index
        __bf16 v = (__bf16)acc[m][n][i];
        if (z == 0)      qb[r * 1024 + cc] = v;
        else if (z == 1) kb[r * 1024 + cc] = v;
        else             vtb[cc * 4096 + r] = v;         // transposed store
      }
}

// PV split-K x2: z=0 -> K [0,2048) into out (fp32), z=1 -> K [2048,4096) into p1.
// A = attn (bf16, ld 8192), B = vT (bf16, ld 4096). M=4096 (y), N=1024 (x).
__global__ __launch_bounds__(256) void pv_gemm(const __bf16* __restrict__ attn,
                                               const __bf16* __restrict__ vt,
                                               float* __restrict__ out,
                                               float* __restrict__ p1) {
  const int z = blockIdx.z;
  float* C = z ? p1 : out;
  const int kbase = z * 2048;
  const long row0 = (long)blockIdx.y * 128;
  const long col0 = (long)blockIdx.x * 128;
  GEMM_PROLOGUE();
  for (int k0 = kbase; k0 < kbase + 2048; k0 += 64) GEMM_KSTEP(attn, 8192, vt, 4096, k0);
#pragma unroll
  for (int m = 0; m < 4; ++m)
#pragma unroll
    for (int n = 0; n < 4; ++n)
#pragma unroll
      for (int i = 0; i < 4; ++i) {
        long r = row0 + wr * 64 + m * 16 + hi * 4 + i;
        long cc = col0 + wc * 64 + n * 16 + lo;
        C[r * 1024 + cc] = acc[m][n][i];
      }
}

__global__ __launch_bounds__(256) void reduce_add(float* __restrict__ out,
                                                  const float* __restrict__ p1) {
  int i = blockIdx.x * 256 + threadIdx.x;  // 1,048,576 float4s
  float4 a = ((const float4*)out)[i];
  float4 b = ((const float4*)p1)[i];
  a.x += b.x; a.y += b.y; a.z += b.z; a.w += b.w;
  ((float4*)out)[i] = a;
}

// One block per row: mask (-1e20 where mask==0), stable softmax of row/32,
// write attn as bf16 IN-PLACE over the fp32 row (attn ld = 8192 bf16 elems).
__global__ __launch_bounds__(256) void softmax_rows(float* __restrict__ sim,
                                                    const int* __restrict__ mask) {
  const int row = blockIdx.x;
  float* rp = sim + (size_t)row * 4096;
  const int4* mrow = (const int4*)(mask + (size_t)row * 4096);
  const int tid = threadIdx.x;

  float vals[16];
  float lmax = -INFINITY;
#pragma unroll
  for (int j = 0; j < 4; ++j) {
    float4 f = ((const float4*)rp)[tid + 256 * j];
    int4 mm = mrow[tid + 256 * j];
    f.x = mm.x ? f.x : -1e20f;
    f.y = mm.y ? f.y : -1e20f;
    f.z = mm.z ? f.z : -1e20f;
    f.w = mm.w ? f.w : -1e20f;
    vals[4 * j + 0] = f.x; vals[4 * j + 1] = f.y;
    vals[4 * j + 2] = f.z; vals[4 * j + 3] = f.w;
    lmax = fmaxf(lmax, fmaxf(fmaxf(f.x, f.y), fmaxf(f.z, f.w)));
  }
#pragma unroll
  for (int off = 32; off; off >>= 1) lmax = fmaxf(lmax, __shfl_xor(lmax, off));
  __shared__ float red[4];
  __shared__ float bro[2];
  if ((tid & 63) == 0) red[tid >> 6] = lmax;
  __syncthreads();
  if (tid == 0) bro[0] = fmaxf(fmaxf(red[0], red[1]), fmaxf(red[2], red[3]));
  __syncthreads();
  const float m = bro[0];

  float e[16];
  float lsum = 0.f;
#pragma unroll
  for (int j = 0; j < 16; ++j) {
    e[j] = __expf((vals[j] - m) * 0.03125f);  // /sqrt(1024)
    lsum += e[j];
  }
#pragma unroll
  for (int off = 32; off; off >>= 1) lsum += __shfl_xor(lsum, off);
  if ((tid & 63) == 0) red[tid >> 6] = lsum;
  __syncthreads();
  if (tid == 0) bro[1] = red[0] + red[1] + red[2] + red[3];
  __syncthreads();
  const float inv = 1.0f / bro[1];

  __bf16* op = (__bf16*)rp;
#pragma unroll
  for (int j = 0; j < 4; ++j) {
    bf16x4 o;
    o[0] = (__bf16)(e[4 * j + 0] * inv);
    o[1] = (__bf16)(e[4 * j + 1] * inv);
    o[2] = (__bf16)(e[4 * j + 2] * inv);
    o[3] = (__bf16)(e[4 * j + 3] * inv);
    ((bf16x4*)op)[tid + 256 * j] = o;
  }
}

extern "C" void kernel_launch(void* const* d_in, const int* in_sizes, int n_in,
                              void* d_out, int out_size, void* d_ws, size_t ws_size,
                              hipStream_t stream) {
  const float* x = (const float*)d_in[0];
  const int* mask = (const int*)d_in[1];
  const float* Wq = (const float*)d_in[2];
  const float* Wk = (const float*)d_in[3];
  const float* Wv = (const float*)d_in[4];
  float* out = (float*)d_out;

  // Workspace layout (102 MB):
  // [0,2M)   Wq bf16   [2M,4M)  Wk bf16   [4M,6M)  Wv bf16
  // [6M,14M) x bf16    [14M,22M) q bf16   [22M,30M) k bf16
  // [30M,38M) vT bf16  [38M,102M) sim fp32 (attn bf16 in-place, ld 8192)
  // PV-time reuse: [0,16M) = split-K partial p1 (W/x region dead by then).
  char* ws = (char*)d_ws;
  __bf16* wqb = (__bf16*)(ws);
  __bf16* wkb = (__bf16*)(ws + (2ull << 20));
  __bf16* wvb = (__bf16*)(ws + (4ull << 20));
  __bf16* xb  = (__bf16*)(ws + (6ull << 20));
  __bf16* qb  = (__bf16*)(ws + (14ull << 20));
  __bf16* kb  = (__bf16*)(ws + (22ull << 20));
  __bf16* vtb = (__bf16*)(ws + (30ull << 20));
  float*  sim = (float*)(ws + (38ull << 20));
  float*  p1  = (float*)(ws);  // 16 MB, reused after q/k/x dead

  cvt_all<<<7168, 256, 0, stream>>>(x, Wq, Wk, Wv, xb, wqb, wkb, wvb);

  dim3 blk(256);
  // q,k,vT in one dispatch: 768 blocks (3 blocks/CU)
  qkv_gemm<<<dim3(8, 32, 3), blk, 0, stream>>>(xb, wqb, wkb, wvb, qb, kb, vtb);
  // sim[i][j] = sum_e q[i,e] k[j,e]  (M=N=4096), raw fp32
  gemm_bt_f32<<<dim3(32, 32), blk, 0, stream>>>(qb, 1024, kb, 1024, sim, 4096, 1024);
  // masked softmax, attn bf16 in-place (ld 8192)
  softmax_rows<<<4096, 256, 0, stream>>>(sim, mask);
  // out[i][j] = sum_k attn[i,k] vT[j,k]; split-K x2 (z=0 -> out, z=1 -> p1)
  pv_gemm<<<dim3(8, 32, 2), blk, 0, stream>>>((const __bf16*)sim, vtb, out, p1);
  reduce_add<<<4096, 256, 0, stream>>>(out, p1);
}